// Round 9
// baseline (87.059 us; speedup 1.0000x reference)
//
#include <hip/hip_runtime.h>
#include <math.h>

constexpr int Bn = 1024, Vn = 5023;
constexpr int NB = 16;            // batches per block (grid y = 64)
constexpr int GB = 4;             // batches sharing one LDS C-read
constexpr int PARAM_STRIDE = 96;  // 36 pose_feat + 5*12 A per batch (floats)
constexpr int ROW_DW = 56;        // fp16-packed row: 54 data + 2 pad dwords

typedef __fp16 half2_t __attribute__((ext_vector_type(2)));

// Force a uniform pointer into SGPRs -> subsequent loads become s_load_*.
__device__ inline const float* sgpr_ptr(const float* p) {
    uintptr_t a = (uintptr_t)p;
    uint32_t lo = (uint32_t)__builtin_amdgcn_readfirstlane((int)(a & 0xFFFFFFFFu));
    uint32_t hi = (uint32_t)__builtin_amdgcn_readfirstlane((int)(a >> 32));
    return (const float*)(((uint64_t)hi << 32) | (uint64_t)lo);
}

// ---------------------------------------------------------------------------
// Kernel A: per-batch pose math. 1 thread per batch.
// params layout per batch: [0..35] pose_feat (joint-1..4, row-major 3x3 - I),
//                          [36..95] A_j as 3x4 row-major, j=0..4
// ---------------------------------------------------------------------------

__device__ inline void rodrigues3(float rx, float ry, float rz, float R[9]) {
    const float eps = 1e-8f;
    float ax = rx + eps, ay = ry + eps, az = rz + eps;
    float ang = sqrtf(ax * ax + ay * ay + az * az);
    float inv = 1.0f / ang;
    float dx = rx * inv, dy = ry * inv, dz = rz * inv;
    float s = sinf(ang), c = cosf(ang), omc = 1.0f - c;
    float K[9] = {0.f, -dz, dy, dz, 0.f, -dx, -dy, dx, 0.f};
    float K2[9];
#pragma unroll
    for (int r = 0; r < 3; r++)
#pragma unroll
        for (int k = 0; k < 3; k++) {
            float acc = 0.f;
#pragma unroll
            for (int i = 0; i < 3; i++) acc += K[r * 3 + i] * K[i * 3 + k];
            K2[r * 3 + k] = acc;
        }
#pragma unroll
    for (int i = 0; i < 9; i++) R[i] = s * K[i] + omc * K2[i];
    R[0] += 1.f; R[4] += 1.f; R[8] += 1.f;
}

__device__ inline void rot6d(const float* x, float R[9]) {
    float a1x = x[0], a1y = x[1], a1z = x[2];
    float a2x = x[3], a2y = x[4], a2z = x[5];
    float n1 = sqrtf(a1x * a1x + a1y * a1y + a1z * a1z);
    float b1x = a1x / n1, b1y = a1y / n1, b1z = a1z / n1;
    float d = b1x * a2x + b1y * a2y + b1z * a2z;
    float tx = a2x - d * b1x, ty = a2y - d * b1y, tz = a2z - d * b1z;
    float n2 = sqrtf(tx * tx + ty * ty + tz * tz);
    float b2x = tx / n2, b2y = ty / n2, b2z = tz / n2;
    float b3x = b1y * b2z - b1z * b2y;
    float b3y = b1z * b2x - b1x * b2z;
    float b3z = b1x * b2y - b1y * b2x;
    R[0] = b1x; R[1] = b1y; R[2] = b1z;
    R[3] = b2x; R[4] = b2y; R[5] = b2z;
    R[6] = b3x; R[7] = b3y; R[8] = b3z;
}

__device__ inline void compose(const float* Rp, const float* tp,
                               const float* Ri, const float* ti,
                               float* Ro, float* to) {
#pragma unroll
    for (int r = 0; r < 3; r++) {
#pragma unroll
        for (int c = 0; c < 3; c++) {
            Ro[r * 3 + c] = Rp[r * 3 + 0] * Ri[0 * 3 + c] +
                            Rp[r * 3 + 1] * Ri[1 * 3 + c] +
                            Rp[r * 3 + 2] * Ri[2 * 3 + c];
        }
        to[r] = Rp[r * 3 + 0] * ti[0] + Rp[r * 3 + 1] * ti[1] +
                Rp[r * 3 + 2] * ti[2] + tp[r];
    }
}

__global__ void flame_params_kernel(const float* __restrict__ g6,
                                    const float* __restrict__ neck,
                                    const float* __restrict__ jaw,
                                    const float* __restrict__ eye,
                                    const float* __restrict__ jrest,
                                    float* __restrict__ params) {
    int b = blockIdx.x * blockDim.x + threadIdx.x;
    if (b >= Bn) return;

    float R[5][9];
    rot6d(g6 + b * 6, R[0]);
    rodrigues3(neck[b * 3 + 0], neck[b * 3 + 1], neck[b * 3 + 2], R[1]);
    rodrigues3(jaw[b * 3 + 0], jaw[b * 3 + 1], jaw[b * 3 + 2], R[2]);
    rodrigues3(eye[b * 6 + 0], eye[b * 6 + 1], eye[b * 6 + 2], R[3]);
    rodrigues3(eye[b * 6 + 3], eye[b * 6 + 4], eye[b * 6 + 5], R[4]);

    float j[5][3];
#pragma unroll
    for (int i = 0; i < 5; i++) {
        j[i][0] = jrest[b * 15 + i * 3 + 0];
        j[i][1] = jrest[b * 15 + i * 3 + 1];
        j[i][2] = jrest[b * 15 + i * 3 + 2];
    }
    float rel[5][3];
#pragma unroll
    for (int c = 0; c < 3; c++) {
        rel[0][c] = j[0][c];
        rel[1][c] = j[1][c] - j[0][c];
        rel[2][c] = j[2][c] - j[1][c];
        rel[3][c] = j[3][c] - j[1][c];
        rel[4][c] = j[4][c] - j[1][c];
    }

    float CR[5][9], CT[5][3];
#pragma unroll
    for (int i = 0; i < 9; i++) CR[0][i] = R[0][i];
#pragma unroll
    for (int c = 0; c < 3; c++) CT[0][c] = rel[0][c];
    compose(CR[0], CT[0], R[1], rel[1], CR[1], CT[1]);
    compose(CR[1], CT[1], R[2], rel[2], CR[2], CT[2]);
    compose(CR[1], CT[1], R[3], rel[3], CR[3], CT[3]);
    compose(CR[1], CT[1], R[4], rel[4], CR[4], CT[4]);

    float* P = params + b * PARAM_STRIDE;
#pragma unroll
    for (int jj = 0; jj < 4; jj++)
#pragma unroll
        for (int r = 0; r < 3; r++)
#pragma unroll
            for (int c = 0; c < 3; c++)
                P[jj * 9 + r * 3 + c] = R[jj + 1][r * 3 + c] - (r == c ? 1.f : 0.f);
#pragma unroll
    for (int i = 0; i < 5; i++) {
#pragma unroll
        for (int r = 0; r < 3; r++) {
            float t = CT[i][r] - (CR[i][r * 3 + 0] * j[i][0] +
                                  CR[i][r * 3 + 1] * j[i][1] +
                                  CR[i][r * 3 + 2] * j[i][2]);
            P[36 + i * 12 + r * 4 + 0] = CR[i][r * 3 + 0];
            P[36 + i * 12 + r * 4 + 1] = CR[i][r * 3 + 1];
            P[36 + i * 12 + r * 4 + 2] = CR[i][r * 3 + 2];
            P[36 + i * 12 + r * 4 + 3] = t;
        }
    }
}

// ---------------------------------------------------------------------------
// Kernel B. R1-R7 unifying diagnosis: per-batch params were per-lane VECTOR
// broadcast loads (SGPR stuck at 80-112 -> never s_load); each pushes
// 64 lanes x 16 B through the TA/vL1D pipe -> ~50us/CU of L1 traffic, the
// ~55-75us floor every structure hit. Fix: readfirstlane'd SGPR pointer ->
// params through the SCALAR cache (s_load_dwordx16, separate pipe). pd in
// fp16 in LDS (v_fma_mix unpacks for free), C-row read once per GB=4
// batches via 14 conflict-free ds_read_b128.
// ---------------------------------------------------------------------------

// static-index access into uint4 C[14] (i literal after unroll)
#define CD(i)                                                        \
    (((i) & 3) == 0 ? C[(i) >> 2].x                                  \
     : ((i) & 3) == 1 ? C[(i) >> 2].y                                \
     : ((i) & 3) == 2 ? C[(i) >> 2].z : C[(i) >> 2].w)
#define ACC(c) ((c) == 0 ? a0 : (c) == 1 ? a1 : a2)

__global__ __launch_bounds__(256, 2) void flame_main_kernel(
    const float* __restrict__ vsh, const float* __restrict__ lbs,
    const float* __restrict__ pdirs, const float* __restrict__ params,
    float* __restrict__ out) {
    int tid = threadIdx.x;
    int v = blockIdx.x * 256 + tid;
    bool valid = v < Vn;
    int vc = valid ? v : (Vn - 1);
    int b0 = blockIdx.y * NB;

    __shared__ uint32_t shd[256 * ROW_DW];  // 57,344 B -> 2 blocks/CU

    // ---- stage: 256 pd rows f32 -> packed fp16 (RTZ), coalesced reads ----
    {
        const size_t blk_base = (size_t)blockIdx.x * 256 * 108;  // dword idx
        const size_t max_base = (size_t)Vn * 108 - 4;
#pragma unroll
        for (int c = 0; c < 27; c++) {
            int q = c * 256 + tid;            // f32-quad index in block region
            size_t src = blk_base + (size_t)q * 4;
            if (src > max_base) src = max_base;
            float4 f = *reinterpret_cast<const float4*>(pdirs + src);
            half2_t h01 = __builtin_amdgcn_cvt_pkrtz(f.x, f.y);
            half2_t h23 = __builtin_amdgcn_cvt_pkrtz(f.z, f.w);
            int p = q * 2;                    // packed-dword index (even)
            int r = p / 54;
            int k = p - r * 54;
            uint2 d;
            d.x = __builtin_bit_cast(uint32_t, h01);
            d.y = __builtin_bit_cast(uint32_t, h23);
            *reinterpret_cast<uint2*>(&shd[r * ROW_DW + k]) = d;  // 8B aligned
        }
    }
    __syncthreads();

    float wgt[5];
#pragma unroll
    for (int jj = 0; jj < 5; jj++) wgt[jj] = lbs[(size_t)vc * 5 + jj];

    const uint4* __restrict__ my =
        reinterpret_cast<const uint4*>(shd + tid * ROW_DW);  // 16B aligned

#pragma unroll 1
    for (int qb = 0; qb < NB / GB; qb++) {
        // one conflict-free LDS row read shared by GB batches
        uint4 C[14];
#pragma unroll
        for (int i = 0; i < 14; i++) C[i] = my[i];

#pragma unroll
        for (int u = 0; u < GB; u++) {
            int b = b0 + qb * GB + u;
            const float* __restrict__ P =
                sgpr_ptr(params + (size_t)b * PARAM_STRIDE);
            size_t base = ((size_t)b * Vn + vc) * 3;

            // v_shaped: the only per-lane VMEM in the loop (plus the store)
            float a0 = vsh[base + 0];
            float a1 = vsh[base + 1];
            float a2 = vsh[base + 2];

            // pose_feat: 36 floats via s_load (SGPRs)
            float fc[36];
#pragma unroll
            for (int g = 0; g < 36; g++) fc[g] = P[g];

            // 108 fp16 pd elements; (float)h fuses into v_fma_mix_f32
#pragma unroll
            for (int i = 0; i < 54; i++) {
                uint32_t dw = CD(i);
                half2_t h = __builtin_bit_cast(half2_t, dw);
                float plo = (float)h.x;
                float phi = (float)h.y;
                const int e0 = 2 * i, e1 = 2 * i + 1;
                ACC(e0 % 3) = fmaf(fc[e0 / 3], plo, ACC(e0 % 3));
                ACC(e1 % 3) = fmaf(fc[e1 / 3], phi, ACC(e1 % 3));
            }

            // LBS: 60 floats via s_load (SGPRs), 75 FMA
            float Af[60];
#pragma unroll
            for (int i = 0; i < 60; i++) Af[i] = P[36 + i];

            float ox = 0.f, oy = 0.f, oz = 0.f;
#pragma unroll
            for (int jj = 0; jj < 5; jj++) {
                const int o = jj * 12;
                float wj = wgt[jj];
                float rx = fmaf(Af[o + 0], a0,
                           fmaf(Af[o + 1], a1, fmaf(Af[o + 2], a2, Af[o + 3])));
                float ry = fmaf(Af[o + 4], a0,
                           fmaf(Af[o + 5], a1, fmaf(Af[o + 6], a2, Af[o + 7])));
                float rz = fmaf(Af[o + 8], a0,
                           fmaf(Af[o + 9], a1, fmaf(Af[o + 10], a2, Af[o + 11])));
                ox = fmaf(wj, rx, ox);
                oy = fmaf(wj, ry, oy);
                oz = fmaf(wj, rz, oz);
            }
            if (valid) {
                out[base + 0] = ox;
                out[base + 1] = oy;
                out[base + 2] = oz;
            }
        }
    }
}

extern "C" void kernel_launch(void* const* d_in, const int* in_sizes, int n_in,
                              void* d_out, int out_size, void* d_ws, size_t ws_size,
                              hipStream_t stream) {
    const float* vsh   = (const float*)d_in[0];
    const float* g6    = (const float*)d_in[1];
    const float* neck  = (const float*)d_in[2];
    const float* jaw   = (const float*)d_in[3];
    const float* eye   = (const float*)d_in[4];
    const float* jrest = (const float*)d_in[5];
    const float* lbs   = (const float*)d_in[6];
    const float* pdirs = (const float*)d_in[7];
    float* out = (float*)d_out;
    float* params = (float*)d_ws;  // Bn * 96 floats = 384 KB

    hipLaunchKernelGGL(flame_params_kernel, dim3((Bn + 255) / 256), dim3(256), 0,
                       stream, g6, neck, jaw, eye, jrest, params);

    dim3 grid((Vn + 255) / 256, Bn / NB);
    hipLaunchKernelGGL(flame_main_kernel, grid, dim3(256), 0, stream, vsh, lbs,
                       pdirs, params, out);
}